// Round 9
// baseline (1131.206 us; speedup 1.0000x reference)
//
#include <hip/hip_runtime.h>

typedef __attribute__((ext_vector_type(4))) float f32x4;
typedef __attribute__((ext_vector_type(8))) short short8;
typedef unsigned short u16;
typedef unsigned int u32;

// B=8, C=512, L=4096, GROUPS=8 (64 ch/group), EPS=1e-5
static constexpr int Bb = 8, Cc = 512, Ll = 4096;

__device__ __forceinline__ u16 f2bf(float f) {
  u32 u = __builtin_bit_cast(u32, f);
  u = (u + 0x7FFFu + ((u >> 16) & 1u)) >> 16;   // RTNE
  return (u16)u;
}

__device__ __forceinline__ void load_lds16(const void* g, void* l) {
  __builtin_amdgcn_global_load_lds((const __attribute__((address_space(1))) void*)g,
                                   (__attribute__((address_space(3))) void*)l,
                                   16, 0, 0);
}

// ---------------- weight fp32 -> bf16 ----------------
__global__ void cvt_bf16_kernel(const float* __restrict__ src, u16* __restrict__ dst, int n) {
  int stride = gridDim.x * blockDim.x;
  for (int i = blockIdx.x * blockDim.x + threadIdx.x; i < n; i += stride)
    dst[i] = f2bf(src[i]);
}

// ---------------- GroupNorm stats: one block per (b,g) ----------------
__global__ __launch_bounds__(256)
void gn_stats_kernel(const float* __restrict__ x, float* __restrict__ stats) {
  int bg = blockIdx.x;  // b*8+g ; group block is contiguous 64*4096 floats
  const f32x4* p = (const f32x4*)(x + (size_t)bg * (64 * Ll));
  float s = 0.f, ss = 0.f;
  for (int i = threadIdx.x; i < 64 * Ll / 4; i += 256) {
    f32x4 v = p[i];
    s  += v[0] + v[1] + v[2] + v[3];
    ss += v[0]*v[0] + v[1]*v[1] + v[2]*v[2] + v[3]*v[3];
  }
  __shared__ float rs[256], rq[256];
  rs[threadIdx.x] = s; rq[threadIdx.x] = ss;
  __syncthreads();
  for (int st = 128; st > 0; st >>= 1) {
    if (threadIdx.x < st) { rs[threadIdx.x] += rs[threadIdx.x + st]; rq[threadIdx.x] += rq[threadIdx.x + st]; }
    __syncthreads();
  }
  if (threadIdx.x == 0) {
    const float inv_n = 1.f / (64.f * 4096.f);
    float mean = rs[0] * inv_n;
    float var  = rq[0] * inv_n - mean * mean;
    stats[bg * 2]     = mean;
    stats[bg * 2 + 1] = rsqrtf(var + 1e-5f);
  }
}

// ------- GN apply + transpose: x[B,C,L] f32 -> xn_t[B,L,C] bf16 -------
__global__ __launch_bounds__(256)
void gn_apply_t_kernel(const float* __restrict__ x, const float* __restrict__ gamma,
                       const float* __restrict__ beta, const float* __restrict__ stats,
                       u16* __restrict__ xn_t) {
  int lt = blockIdx.x;   // l tile (64)
  int ct = blockIdx.y;   // c tile (64) == group index (64 ch/group)
  int b  = blockIdx.z;
  __shared__ float tile[64][65];
  int t = threadIdx.x;
  int lx = t & 63;       // lane within row
  int qd = t >> 6;       // quarter 0..3
  int c0 = ct * 64, l0 = lt * 64;
  float mean = stats[(b * 8 + ct) * 2];
  float rstd = stats[(b * 8 + ct) * 2 + 1];
  #pragma unroll
  for (int i = 0; i < 16; ++i) {
    int cl = qd + i * 4;
    int c = c0 + cl;
    float v = x[((size_t)b * Cc + c) * Ll + l0 + lx];
    tile[cl][lx] = (v - mean) * rstd * gamma[c] + beta[c];
  }
  __syncthreads();
  #pragma unroll
  for (int i = 0; i < 16; ++i) {
    int ll = qd + i * 4;
    xn_t[((size_t)b * Ll + l0 + ll) * Cc + c0 + lx] = f2bf(tile[lx][ll]);
  }
}

// ---------------- TN GEMM: D[m][n] = sum_k A[m][k]*Bm[n][k] ----------------
// A: [M][lda] bf16 (k contiguous), Bm: [N][ldb] bf16 (k contiguous).
// LDS layout is granule-transposed for full-row b128 reads:
//  slot(r,g) = ((r>>4)*16 + (g>>2)*8 + (r&7))*8 + ((r>>3)&1)*4 + (g&3)
// MODE 0: bias[n], bf16 out. MODE 1: bias[m], bf16 out. MODE 2: bias[m] + resid, f32 out.
template <int MODE>
__global__ __launch_bounds__(256, 2)
void gemm_tn(const u16* __restrict__ A, long long aStride, int lda,
             const u16* __restrict__ Bm, long long bStride, int ldb,
             void* __restrict__ Dv, long long dStride, int ldd,
             const float* __restrict__ bias, const float* __restrict__ resid, int K) {
  int z = blockIdx.z;
  A  += (size_t)z * aStride;
  Bm += (size_t)z * bStride;
  int m0 = blockIdx.x * 128, n0 = blockIdx.y * 128;
  __shared__ uint4 sA[1024], sB[1024];
  int tid = threadIdx.x, lane = tid & 63;
  int wv = tid >> 6, wr = wv >> 1, wc = wv & 1;
  int l15 = lane & 15, l4 = lane >> 4;
  f32x4 acc[4][4] = {};
  for (int kt = 0; kt < K; kt += 64) {
    __syncthreads();
    #pragma unroll
    for (int p = 0; p < 4; ++p) {
      int s = p * 256 + tid;
      int r = ((s >> 7) << 4) | (((s >> 2) & 1) << 3) | ((s >> 3) & 7);
      int g = (((s >> 6) & 1) << 2) | (s & 3);
      load_lds16(A  + (size_t)(m0 + r) * lda + kt + g * 8, &sA[s]);
      load_lds16(Bm + (size_t)(n0 + r) * ldb + kt + g * 8, &sB[s]);
    }
    __syncthreads();
    #pragma unroll
    for (int ks = 0; ks < 2; ++ks) {
      short8 af[4], bfr[4];
      #pragma unroll
      for (int i = 0; i < 4; ++i) {
        int sa = (4 * wr + i) * 128 + ks * 64 + (l15 & 7) * 8 + (l15 >> 3) * 4 + l4;
        af[i]  = *(const short8*)&sA[sa];
        int sb = (4 * wc + i) * 128 + ks * 64 + (l15 & 7) * 8 + (l15 >> 3) * 4 + l4;
        bfr[i] = *(const short8*)&sB[sb];
      }
      #pragma unroll
      for (int i = 0; i < 4; ++i)
        #pragma unroll
        for (int j = 0; j < 4; ++j)
          acc[i][j] = __builtin_amdgcn_mfma_f32_16x16x32_bf16(af[i], bfr[j], acc[i][j], 0, 0, 0);
    }
  }
  #pragma unroll
  for (int i = 0; i < 4; ++i) {
    #pragma unroll
    for (int j = 0; j < 4; ++j) {
      #pragma unroll
      for (int r = 0; r < 4; ++r) {
        int m = m0 + 64 * wr + 16 * i + 4 * l4 + r;
        int n = n0 + 64 * wc + 16 * j + l15;
        float val = acc[i][j][r] + (MODE == 0 ? bias[n] : bias[m]);
        size_t idx = (size_t)z * dStride + (size_t)m * ldd + n;
        if (MODE == 2) ((float*)Dv)[idx] = val + resid[idx];
        else           ((u16*)Dv)[idx]   = f2bf(val);
      }
    }
  }
}

// ---- Flash attention: 64k tiles, single-buffered, 3-barrier split-phase prefetch ----
// qk_t[b][l][0:512]=q, [512:1024]=k (bf16, row stride 1024); v[b][c][l] bf16.
// Out: o_t[b][l][c] bf16. Grid: 256 blocks 1D; batch = bid & 7 (XCD-pinned).
// Schedule per 64k iter:
//   [vmcnt(8): K(kt) landed, V(kt) in flight] bar1 -> QK+softmax+P-write
//   [vmcnt(0)+lgkm: V landed, P visible, sK free] bar2 -> issue K(kt+1) -> rescale+PV
//   [lgkm: sV/sP reads done] bar3 -> issue V(kt+1)
__global__ __launch_bounds__(512, 2)
void flash_attn_kernel(const u16* __restrict__ qk_t, const u16* __restrict__ v,
                       u16* __restrict__ o_t) {
  int bid = blockIdx.x;
  int b  = bid & 7;
  int q0 = (bid >> 3) * 128;
  int tid = threadIdx.x, lane = tid & 63, wv = tid >> 6;
  int l15 = lane & 15, l4 = lane >> 4;
  const u16* qkb = qk_t + (size_t)b * Ll * 1024;
  const u16* vb  = v    + (size_t)b * Cc * Ll;
  u16* ob        = o_t  + (size_t)b * Ll * Cc;

  __shared__ uint4 sK[64 * 64];      // 64 KB: [64 k-rows][64 granules], XOR swizzle
  __shared__ uint4 sV[512 * 8];      // 64 KB: [512 c-rows][8 granules], XOR swizzle
  __shared__ __align__(16) char sP[128 * 144];  // P[128 q][64 k] bf16, row stride 144 B
  __shared__ __align__(16) float sAl[128];      // per-q rescale / final lrun

  int ow_q = wv >> 2, ow_c = wv & 3;  // PV-phase wave -> O tile [64 q][128 c]

  // Q fragments (B-operand of swapped QK): col=q=l15 of wave's 16-q block
  short8 aq[16];
  {
    const u16* qp = qkb + (size_t)(q0 + wv * 16 + l15) * 1024 + 8 * l4;
    #pragma unroll
    for (int ks = 0; ks < 16; ++ks) aq[ks] = *(const short8*)(qp + 32 * ks);
  }

  auto issueK = [&](int kt) {    // 8 loads/thread: 64 rows x 512 c
    #pragma unroll
    for (int p = 0; p < 8; ++p) {
      int s = p * 512 + tid;
      int r = s >> 6, g = s & 63, gw = g ^ (r & 7);
      load_lds16(qkb + (size_t)(kt * 64 + r) * 1024 + 512 + gw * 8, &sK[s]);
    }
  };
  auto issueV = [&](int kt) {    // 8 loads/thread: 512 c-rows x 64 k
    #pragma unroll
    for (int p = 0; p < 8; ++p) {
      int s = p * 512 + tid;
      int r = s >> 3, g = s & 7, gw = g ^ (r & 7);
      load_lds16(vb + (size_t)r * Ll + kt * 64 + gw * 8, &sV[s]);
    }
  };
  issueK(0);
  issueV(0);

  f32x4 accO[4][8];
  #pragma unroll
  for (int i = 0; i < 4; ++i)
    #pragma unroll
    for (int j = 0; j < 8; ++j) accO[i][j] = (f32x4){0.f, 0.f, 0.f, 0.f};
  float mrun = -1e30f, lrun = 0.f;      // lane owns q-row = l15 (of wave's 16-q block)
  const float scale = 0.044194173824159216f;  // 512^-0.5

  const int NT = Ll / 64;
  for (int kt = 0; kt < NT; ++kt) {
    // ---- bar1: K(kt) landed (V(kt)'s 8 loads stay in flight: T4) ----
    asm volatile("s_waitcnt vmcnt(8)" ::: "memory");
    __builtin_amdgcn_s_barrier();
    __builtin_amdgcn_sched_barrier(0);

    // ---- QK^T swapped: s2[t] = mfma(K_frag, Q) -> lane: S[k=16t+4*l4+r][q=l15] ----
    f32x4 s2[4];
    #pragma unroll
    for (int t = 0; t < 4; ++t) {
      s2[t] = (f32x4){0.f, 0.f, 0.f, 0.f};
      int krow = 16 * t + l15;
      #pragma unroll
      for (int ks = 0; ks < 16; ++ks) {
        short8 ak = *(const short8*)&sK[krow * 64 + ((4 * ks + l4) ^ (krow & 7))];
        s2[t] = __builtin_amdgcn_mfma_f32_16x16x32_bf16(ak, aq[ks], s2[t], 0, 0, 0);
      }
    }

    // ---- online softmax over this 64k slice ----
    #pragma unroll
    for (int t = 0; t < 4; ++t)
      #pragma unroll
      for (int r = 0; r < 4; ++r) s2[t][r] *= scale;
    float mx = -1e30f;
    #pragma unroll
    for (int t = 0; t < 4; ++t)
      #pragma unroll
      for (int r = 0; r < 4; ++r) mx = fmaxf(mx, s2[t][r]);
    mx = fmaxf(mx, __shfl_xor(mx, 16));
    mx = fmaxf(mx, __shfl_xor(mx, 32));
    float mnew = fmaxf(mrun, mx);
    float al = __expf(mrun - mnew);
    mrun = mnew;
    float ps = 0.f;
    #pragma unroll
    for (int t = 0; t < 4; ++t)
      #pragma unroll
      for (int r = 0; r < 4; ++r) { float pv = __expf(s2[t][r] - mnew); s2[t][r] = pv; ps += pv; }
    ps += __shfl_xor(ps, 16);
    ps += __shfl_xor(ps, 32);
    lrun = lrun * al + ps;

    // ---- P -> block-shared LDS (row stride 144 B) + al ----
    {
      char* pb = sP + (16 * wv + l15) * 144;
      #pragma unroll
      for (int t = 0; t < 4; ++t) {
        u32 lo = (u32)f2bf(s2[t][0]) | ((u32)f2bf(s2[t][1]) << 16);
        u32 hi = (u32)f2bf(s2[t][2]) | ((u32)f2bf(s2[t][3]) << 16);
        uint2 w = {lo, hi};
        *(uint2*)(pb + 32 * t + 8 * l4) = w;   // k = 16t+4*l4 .. +3 of row q
      }
      if (lane < 16) sAl[16 * wv + lane] = al;
    }

    // ---- bar2: V(kt) drained, P/al visible, sK free ----
    __builtin_amdgcn_sched_barrier(0);
    asm volatile("s_waitcnt vmcnt(0) lgkmcnt(0)" ::: "memory");
    __builtin_amdgcn_s_barrier();
    __builtin_amdgcn_sched_barrier(0);
    if (kt + 1 < NT) issueK(kt + 1);   // covered by PV below

    // ---- rescale accO rows by per-q factors ----
    #pragma unroll
    for (int i = 0; i < 4; ++i) {
      f32x4 av = *(const f32x4*)&sAl[64 * ow_q + 16 * i + 4 * l4];
      #pragma unroll
      for (int j = 0; j < 8; ++j) {
        #pragma unroll
        for (int r = 0; r < 4; ++r) accO[i][j][r] *= av[r];
      }
    }
    // ---- PV: O tile [64 q][128 c] per wave; A=P shared, B=V; k-depth 64 = 2 MFMA ----
    #pragma unroll
    for (int ks = 0; ks < 2; ++ks) {
      short8 ap[4];
      #pragma unroll
      for (int i = 0; i < 4; ++i) {
        int ra = 64 * ow_q + 16 * i + l15;
        ap[i] = *(const short8*)(sP + ra * 144 + 64 * ks + 16 * l4);
      }
      #pragma unroll
      for (int j = 0; j < 8; ++j) {
        int crow = 128 * ow_c + 16 * j + l15;
        short8 bv = *(const short8*)&sV[crow * 8 + ((4 * ks + l4) ^ (crow & 7))];
        #pragma unroll
        for (int i = 0; i < 4; ++i)
          accO[i][j] = __builtin_amdgcn_mfma_f32_16x16x32_bf16(ap[i], bv, accO[i][j], 0, 0, 0);
      }
    }

    // ---- bar3: sV/sP reads retired -> safe to restage V ----
    __builtin_amdgcn_sched_barrier(0);
    asm volatile("s_waitcnt lgkmcnt(0)" ::: "memory");
    __builtin_amdgcn_s_barrier();
    __builtin_amdgcn_sched_barrier(0);
    if (kt + 1 < NT) issueV(kt + 1);   // covered by next iter's QK
  }

  // ---- relay lrun through sAl, normalize, write o_t[b][q][c] bf16 ----
  if (lane < 16) sAl[16 * wv + lane] = lrun;
  __syncthreads();
  #pragma unroll
  for (int i = 0; i < 4; ++i) {
    f32x4 lv = *(const f32x4*)&sAl[64 * ow_q + 16 * i + 4 * l4];
    #pragma unroll
    for (int r = 0; r < 4; ++r) lv[r] = 1.f / lv[r];
    #pragma unroll
    for (int j = 0; j < 8; ++j) {
      #pragma unroll
      for (int r = 0; r < 4; ++r) {
        int q = q0 + 64 * ow_q + 16 * i + 4 * l4 + r;
        int c = 128 * ow_c + 16 * j + l15;
        ob[(size_t)q * Cc + c] = f2bf(accO[i][j][r] * lv[r]);
      }
    }
  }
}

extern "C" void kernel_launch(void* const* d_in, const int* in_sizes, int n_in,
                              void* d_out, int out_size, void* d_ws, size_t ws_size,
                              hipStream_t stream) {
  const float* x     = (const float*)d_in[0];
  const float* gamma = (const float*)d_in[1];
  const float* beta  = (const float*)d_in[2];
  const float* w_qkv = (const float*)d_in[3];
  const float* b_qkv = (const float*)d_in[4];
  const float* w_out = (const float*)d_in[5];
  const float* b_out = (const float*)d_in[6];
  float* out = (float*)d_out;

  char* ws = (char*)d_ws;
  size_t off = 0;
  auto alloc = [&](size_t bytes) -> char* {
    char* p = ws + off;
    off += (bytes + 1023) & ~(size_t)1023;
    return p;
  };
  float* stats = (float*)alloc(64 * 2 * sizeof(float));
  u16* wqb = (u16*)alloc((size_t)1536 * 512 * 2);
  u16* wob = (u16*)alloc((size_t)512 * 512 * 2);
  u16* xnt = (u16*)alloc((size_t)Bb * Ll * Cc * 2);   // [B][L][C]
  u16* qkt = (u16*)alloc((size_t)Bb * Ll * 1024 * 2); // [B][L][1024] (q|k)
  u16* vbf = (u16*)alloc((size_t)Bb * Cc * Ll * 2);   // [B][C][L]
  u16* ot  = xnt;  // reuse: xn_t dead after QKV GEMMs
  if (off > ws_size) return;  // workspace too small: fail loudly via validation

  cvt_bf16_kernel<<<256, 256, 0, stream>>>(w_qkv, wqb, 1536 * 512);
  cvt_bf16_kernel<<<256, 256, 0, stream>>>(w_out, wob, 512 * 512);
  gn_stats_kernel<<<64, 256, 0, stream>>>(x, stats);
  gn_apply_t_kernel<<<dim3(64, 8, 8), 256, 0, stream>>>(x, gamma, beta, stats, xnt);
  // qk_t[b][l][o] = sum_c xn_t[b][l][c] * w_qkv[o][c] + b_qkv[o], o in [0,1024)
  gemm_tn<0><<<dim3(32, 8, 8), 256, 0, stream>>>(
      xnt, (long long)Ll * Cc, Cc, wqb, 0, Cc,
      qkt, (long long)Ll * 1024, 1024, b_qkv, nullptr, Cc);
  // v[b][c][l] = sum_cc w_qkv[1024+c][cc] * xn_t[b][l][cc] + b_qkv[1024+c]
  gemm_tn<1><<<dim3(4, 32, 8), 256, 0, stream>>>(
      wqb + (size_t)1024 * 512, 0, Cc, xnt, (long long)Ll * Cc, Cc,
      vbf, (long long)Cc * Ll, Ll, b_qkv + 1024, nullptr, Cc);
  flash_attn_kernel<<<256, 512, 0, stream>>>(qkt, vbf, ot);
  // out[b][o][l] = x + sum_c w_out[o][c] * o_t[b][l][c] + b_out[o]
  gemm_tn<2><<<dim3(4, 32, 8), 256, 0, stream>>>(
      wob, 0, Cc, ot, (long long)Ll * Cc, Cc,
      out, (long long)Cc * Ll, Ll, b_out, x, Cc);
}

// Round 10
// 668.194 us; speedup vs baseline: 1.6929x; 1.6929x over previous
//
#include <hip/hip_runtime.h>

typedef __attribute__((ext_vector_type(4))) float f32x4;
typedef __attribute__((ext_vector_type(8))) short short8;
typedef unsigned short u16;
typedef unsigned int u32;

// B=8, C=512, L=4096, GROUPS=8 (64 ch/group), EPS=1e-5
static constexpr int Bb = 8, Cc = 512, Ll = 4096;

__device__ __forceinline__ u16 f2bf(float f) {
  u32 u = __builtin_bit_cast(u32, f);
  u = (u + 0x7FFFu + ((u >> 16) & 1u)) >> 16;   // RTNE
  return (u16)u;
}

__device__ __forceinline__ void load_lds16(const void* g, void* l) {
  __builtin_amdgcn_global_load_lds((const __attribute__((address_space(1))) void*)g,
                                   (__attribute__((address_space(3))) void*)l,
                                   16, 0, 0);
}

// ---------------- weight fp32 -> bf16 ----------------
__global__ void cvt_bf16_kernel(const float* __restrict__ src, u16* __restrict__ dst, int n) {
  int stride = gridDim.x * blockDim.x;
  for (int i = blockIdx.x * blockDim.x + threadIdx.x; i < n; i += stride)
    dst[i] = f2bf(src[i]);
}

// ---------------- GroupNorm stats: one block per (b,g) ----------------
__global__ __launch_bounds__(256)
void gn_stats_kernel(const float* __restrict__ x, float* __restrict__ stats) {
  int bg = blockIdx.x;  // b*8+g ; group block is contiguous 64*4096 floats
  const f32x4* p = (const f32x4*)(x + (size_t)bg * (64 * Ll));
  float s = 0.f, ss = 0.f;
  for (int i = threadIdx.x; i < 64 * Ll / 4; i += 256) {
    f32x4 v = p[i];
    s  += v[0] + v[1] + v[2] + v[3];
    ss += v[0]*v[0] + v[1]*v[1] + v[2]*v[2] + v[3]*v[3];
  }
  __shared__ float rs[256], rq[256];
  rs[threadIdx.x] = s; rq[threadIdx.x] = ss;
  __syncthreads();
  for (int st = 128; st > 0; st >>= 1) {
    if (threadIdx.x < st) { rs[threadIdx.x] += rs[threadIdx.x + st]; rq[threadIdx.x] += rq[threadIdx.x + st]; }
    __syncthreads();
  }
  if (threadIdx.x == 0) {
    const float inv_n = 1.f / (64.f * 4096.f);
    float mean = rs[0] * inv_n;
    float var  = rq[0] * inv_n - mean * mean;
    stats[bg * 2]     = mean;
    stats[bg * 2 + 1] = rsqrtf(var + 1e-5f);
  }
}

// ------- GN apply + transpose: x[B,C,L] f32 -> xn_t[B,L,C] bf16 -------
__global__ __launch_bounds__(256)
void gn_apply_t_kernel(const float* __restrict__ x, const float* __restrict__ gamma,
                       const float* __restrict__ beta, const float* __restrict__ stats,
                       u16* __restrict__ xn_t) {
  int lt = blockIdx.x;   // l tile (64)
  int ct = blockIdx.y;   // c tile (64) == group index (64 ch/group)
  int b  = blockIdx.z;
  __shared__ float tile[64][65];
  int t = threadIdx.x;
  int lx = t & 63;       // lane within row
  int qd = t >> 6;       // quarter 0..3
  int c0 = ct * 64, l0 = lt * 64;
  float mean = stats[(b * 8 + ct) * 2];
  float rstd = stats[(b * 8 + ct) * 2 + 1];
  #pragma unroll
  for (int i = 0; i < 16; ++i) {
    int cl = qd + i * 4;
    int c = c0 + cl;
    float v = x[((size_t)b * Cc + c) * Ll + l0 + lx];
    tile[cl][lx] = (v - mean) * rstd * gamma[c] + beta[c];
  }
  __syncthreads();
  #pragma unroll
  for (int i = 0; i < 16; ++i) {
    int ll = qd + i * 4;
    xn_t[((size_t)b * Ll + l0 + ll) * Cc + c0 + lx] = f2bf(tile[lx][ll]);
  }
}

// ---------------- TN GEMM: D[m][n] = sum_k A[m][k]*Bm[n][k] ----------------
// A: [M][lda] bf16 (k contiguous), Bm: [N][ldb] bf16 (k contiguous).
// LDS layout is granule-transposed for full-row b128 reads:
//  slot(r,g) = ((r>>4)*16 + (g>>2)*8 + (r&7))*8 + ((r>>3)&1)*4 + (g&3)
// MODE 0: bias[n], bf16 out. MODE 1: bias[m], bf16 out. MODE 2: bias[m] + resid, f32 out.
template <int MODE>
__global__ __launch_bounds__(256, 2)
void gemm_tn(const u16* __restrict__ A, long long aStride, int lda,
             const u16* __restrict__ Bm, long long bStride, int ldb,
             void* __restrict__ Dv, long long dStride, int ldd,
             const float* __restrict__ bias, const float* __restrict__ resid, int K) {
  int z = blockIdx.z;
  A  += (size_t)z * aStride;
  Bm += (size_t)z * bStride;
  int m0 = blockIdx.x * 128, n0 = blockIdx.y * 128;
  __shared__ uint4 sA[1024], sB[1024];
  int tid = threadIdx.x, lane = tid & 63;
  int wv = tid >> 6, wr = wv >> 1, wc = wv & 1;
  int l15 = lane & 15, l4 = lane >> 4;
  f32x4 acc[4][4] = {};
  for (int kt = 0; kt < K; kt += 64) {
    __syncthreads();
    #pragma unroll
    for (int p = 0; p < 4; ++p) {
      int s = p * 256 + tid;
      int r = ((s >> 7) << 4) | (((s >> 2) & 1) << 3) | ((s >> 3) & 7);
      int g = (((s >> 6) & 1) << 2) | (s & 3);
      load_lds16(A  + (size_t)(m0 + r) * lda + kt + g * 8, &sA[s]);
      load_lds16(Bm + (size_t)(n0 + r) * ldb + kt + g * 8, &sB[s]);
    }
    __syncthreads();
    #pragma unroll
    for (int ks = 0; ks < 2; ++ks) {
      short8 af[4], bfr[4];
      #pragma unroll
      for (int i = 0; i < 4; ++i) {
        int sa = (4 * wr + i) * 128 + ks * 64 + (l15 & 7) * 8 + (l15 >> 3) * 4 + l4;
        af[i]  = *(const short8*)&sA[sa];
        int sb = (4 * wc + i) * 128 + ks * 64 + (l15 & 7) * 8 + (l15 >> 3) * 4 + l4;
        bfr[i] = *(const short8*)&sB[sb];
      }
      #pragma unroll
      for (int i = 0; i < 4; ++i)
        #pragma unroll
        for (int j = 0; j < 4; ++j)
          acc[i][j] = __builtin_amdgcn_mfma_f32_16x16x32_bf16(af[i], bfr[j], acc[i][j], 0, 0, 0);
    }
  }
  #pragma unroll
  for (int i = 0; i < 4; ++i) {
    #pragma unroll
    for (int j = 0; j < 4; ++j) {
      #pragma unroll
      for (int r = 0; r < 4; ++r) {
        int m = m0 + 64 * wr + 16 * i + 4 * l4 + r;
        int n = n0 + 64 * wc + 16 * j + l15;
        float val = acc[i][j][r] + (MODE == 0 ? bias[n] : bias[m]);
        size_t idx = (size_t)z * dStride + (size_t)m * ldd + n;
        if (MODE == 2) ((float*)Dv)[idx] = val + resid[idx];
        else           ((u16*)Dv)[idx]   = f2bf(val);
      }
    }
  }
}

// ---------------- Flash attention (R5 structure, sP stride 80) ----------------
// qk_t[b][l][0:512]=q, [512:1024]=k (bf16, row stride 1024); v[b][c][l] bf16.
// Out: o_t[b][l][c] bf16. Grid: 256 blocks 1D; batch = bid & 7 (XCD-pinned).
// Tile working set 64 KB/iter: 32 blocks/XCD x 64 KB = 2 MB <= L2/2 (feasibility law, R9).
__global__ __launch_bounds__(512, 2)
void flash_attn_kernel(const u16* __restrict__ qk_t, const u16* __restrict__ v,
                       u16* __restrict__ o_t) {
  int bid = blockIdx.x;
  int b  = bid & 7;
  int q0 = (bid >> 3) * 128;
  int tid = threadIdx.x, lane = tid & 63, wv = tid >> 6;
  int l15 = lane & 15, l4 = lane >> 4;
  const u16* qkb = qk_t + (size_t)b * Ll * 1024;
  const u16* vb  = v    + (size_t)b * Cc * Ll;
  u16* ob        = o_t  + (size_t)b * Ll * Cc;

  __shared__ uint4 sK[2][32 * 64];      // 2 x 32 KB: granule-transposed full-row layout (R5)
  __shared__ uint4 sV[2][512 * 4];      // 2 x 32 KB: [512 c-rows][4 granules], parity-XOR (R4)
  __shared__ __align__(16) char sP[128 * 80];  // P[128 q][32 k] bf16, row stride 80 B
  __shared__ __align__(16) float sAl[128];     // per-q rescale / final lrun

  int ow_q = wv >> 2, ow_c = wv & 3;    // PV-phase wave -> O tile [64 q][128 c]

  // Q fragments (B-operand of swapped QK): col=q=l15 of wave's 16-q block
  short8 aq[16];
  {
    const u16* qp = qkb + (size_t)(q0 + wv * 16 + l15) * 1024 + 8 * l4;
    #pragma unroll
    for (int ks = 0; ks < 16; ++ks) aq[ks] = *(const short8*)(qp + 32 * ks);
  }

  auto issueK = [&](int kt, int buf) {
    #pragma unroll
    for (int p = 0; p < 4; ++p) {
      int s = p * 512 + tid;
      int kr = (((s >> 6) & 1) << 4) | (((s >> 2) & 1) << 3) | ((s >> 3) & 7);
      int g  = ((s >> 7) << 2) | (s & 3);
      load_lds16(qkb + (size_t)(kt * 32 + kr) * 1024 + 512 + g * 8, &sK[buf][s]);
    }
  };
  auto issueV = [&](int kt, int buf) {
    #pragma unroll
    for (int p = 0; p < 4; ++p) {
      int s = p * 512 + tid;
      int r = s >> 2, g = s & 3, gw = g ^ ((r >> 1) & 3);
      load_lds16(vb + (size_t)r * Ll + kt * 32 + gw * 8, &sV[buf][s]);
    }
  };
  issueK(0, 0);
  issueV(0, 0);

  f32x4 accO[4][8];
  #pragma unroll
  for (int i = 0; i < 4; ++i)
    #pragma unroll
    for (int j = 0; j < 8; ++j) accO[i][j] = (f32x4){0.f, 0.f, 0.f, 0.f};
  float mrun = -1e30f, lrun = 0.f;      // lane owns q-row = l15 (of wave's 16-q block)
  const float scale = 0.044194173824159216f;  // 512^-0.5

  const int NT = Ll / 32;
  for (int kt = 0; kt < NT; ++kt) {
    int buf = kt & 1;
    __syncthreads();   // stage(kt) landed (issued a full iter ago); prev PV reads done
    if (kt + 1 < NT) { issueK(kt + 1, buf ^ 1); issueV(kt + 1, buf ^ 1); }

    // ---- QK^T swapped: s2[t] = mfma(K_frag, Q) -> lane: S[k=16t+4*l4+r][q=l15] ----
    const uint4* kb = &sK[buf][0];
    f32x4 s2[2];
    #pragma unroll
    for (int t = 0; t < 2; ++t) {
      s2[t] = (f32x4){0.f, 0.f, 0.f, 0.f};
      #pragma unroll
      for (int ks = 0; ks < 16; ++ks) {
        // full-row read: 8 complete 128B rows per wave instruction
        short8 ak = *(const short8*)&kb[ks * 128 + t * 64 + (l15 & 7) * 8 + (l15 >> 3) * 4 + l4];
        s2[t] = __builtin_amdgcn_mfma_f32_16x16x32_bf16(ak, aq[ks], s2[t], 0, 0, 0);
      }
    }

    // ---- online softmax over this 32k slice (q=l15 spread across l4 groups) ----
    #pragma unroll
    for (int t = 0; t < 2; ++t)
      #pragma unroll
      for (int r = 0; r < 4; ++r) s2[t][r] *= scale;
    float mx = fmaxf(fmaxf(s2[0][0], s2[0][1]), fmaxf(s2[0][2], s2[0][3]));
    mx = fmaxf(mx, fmaxf(fmaxf(s2[1][0], s2[1][1]), fmaxf(s2[1][2], s2[1][3])));
    mx = fmaxf(mx, __shfl_xor(mx, 16));
    mx = fmaxf(mx, __shfl_xor(mx, 32));
    float mnew = fmaxf(mrun, mx);
    float al = __expf(mrun - mnew);
    mrun = mnew;
    float ps = 0.f;
    #pragma unroll
    for (int t = 0; t < 2; ++t)
      #pragma unroll
      for (int r = 0; r < 4; ++r) { float pv = __expf(s2[t][r] - mnew); s2[t][r] = pv; ps += pv; }
    ps += __shfl_xor(ps, 16);
    ps += __shfl_xor(ps, 32);
    lrun = lrun * al + ps;

    // ---- P -> block-shared LDS (row stride 80 B, packed uint2) + al ----
    {
      char* pb = sP + (16 * wv + l15) * 80;
      #pragma unroll
      for (int t = 0; t < 2; ++t) {
        u32 lo = (u32)f2bf(s2[t][0]) | ((u32)f2bf(s2[t][1]) << 16);
        u32 hi = (u32)f2bf(s2[t][2]) | ((u32)f2bf(s2[t][3]) << 16);
        uint2 w = {lo, hi};
        *(uint2*)(pb + 32 * t + 8 * l4) = w;   // k = 16t+4*l4 .. +3 of row q
      }
      if (lane < 16) sAl[16 * wv + lane] = al;
    }

    // ---- publish P/al (lgkm only — staged prefetch stays in flight: T4) ----
    __builtin_amdgcn_sched_barrier(0);
    asm volatile("s_waitcnt lgkmcnt(0)" ::: "memory");
    __builtin_amdgcn_s_barrier();
    __builtin_amdgcn_sched_barrier(0);

    // ---- rescale accO rows by per-q factors ----
    #pragma unroll
    for (int i = 0; i < 4; ++i) {
      f32x4 av = *(const f32x4*)&sAl[64 * ow_q + 16 * i + 4 * l4];
      #pragma unroll
      for (int j = 0; j < 8; ++j) {
        #pragma unroll
        for (int r = 0; r < 4; ++r) accO[i][j][r] *= av[r];
      }
    }
    // ---- PV: O tile [64 q][128 c] per wave; A=P (shared), B=V; k-depth 32 = 1 MFMA ----
    short8 ap[4];
    #pragma unroll
    for (int i = 0; i < 4; ++i) {
      int ra = 64 * ow_q + 16 * i + l15;
      ap[i] = *(const short8*)(sP + ra * 80 + 16 * l4);
    }
    const uint4* vbuf = &sV[buf][0];
    #pragma unroll
    for (int j = 0; j < 8; ++j) {
      int crow = 128 * ow_c + 16 * j + l15;
      short8 bv = *(const short8*)&vbuf[crow * 4 + (l4 ^ ((crow >> 1) & 3))];
      #pragma unroll
      for (int i = 0; i < 4; ++i)
        accO[i][j] = __builtin_amdgcn_mfma_f32_16x16x32_bf16(ap[i], bv, accO[i][j], 0, 0, 0);
    }
  }

  // ---- relay lrun through sAl, normalize, write o_t[b][q][c] bf16 ----
  __syncthreads();
  if (lane < 16) sAl[16 * wv + lane] = lrun;
  __syncthreads();
  #pragma unroll
  for (int i = 0; i < 4; ++i) {
    f32x4 lv = *(const f32x4*)&sAl[64 * ow_q + 16 * i + 4 * l4];
    #pragma unroll
    for (int r = 0; r < 4; ++r) lv[r] = 1.f / lv[r];
    #pragma unroll
    for (int j = 0; j < 8; ++j) {
      #pragma unroll
      for (int r = 0; r < 4; ++r) {
        int q = q0 + 64 * ow_q + 16 * i + 4 * l4 + r;
        int c = 128 * ow_c + 16 * j + l15;
        ob[(size_t)q * Cc + c] = f2bf(accO[i][j][r] * lv[r]);
      }
    }
  }
}

extern "C" void kernel_launch(void* const* d_in, const int* in_sizes, int n_in,
                              void* d_out, int out_size, void* d_ws, size_t ws_size,
                              hipStream_t stream) {
  const float* x     = (const float*)d_in[0];
  const float* gamma = (const float*)d_in[1];
  const float* beta  = (const float*)d_in[2];
  const float* w_qkv = (const float*)d_in[3];
  const float* b_qkv = (const float*)d_in[4];
  const float* w_out = (const float*)d_in[5];
  const float* b_out = (const float*)d_in[6];
  float* out = (float*)d_out;

  char* ws = (char*)d_ws;
  size_t off = 0;
  auto alloc = [&](size_t bytes) -> char* {
    char* p = ws + off;
    off += (bytes + 1023) & ~(size_t)1023;
    return p;
  };
  float* stats = (float*)alloc(64 * 2 * sizeof(float));
  u16* wqb = (u16*)alloc((size_t)1536 * 512 * 2);
  u16* wob = (u16*)alloc((size_t)512 * 512 * 2);
  u16* xnt = (u16*)alloc((size_t)Bb * Ll * Cc * 2);   // [B][L][C]
  u16* qkt = (u16*)alloc((size_t)Bb * Ll * 1024 * 2); // [B][L][1024] (q|k)
  u16* vbf = (u16*)alloc((size_t)Bb * Cc * Ll * 2);   // [B][C][L]
  u16* ot  = xnt;  // reuse: xn_t dead after QKV GEMMs
  if (off > ws_size) return;  // workspace too small: fail loudly via validation

  cvt_bf16_kernel<<<256, 256, 0, stream>>>(w_qkv, wqb, 1536 * 512);
  cvt_bf16_kernel<<<256, 256, 0, stream>>>(w_out, wob, 512 * 512);
  gn_stats_kernel<<<64, 256, 0, stream>>>(x, stats);
  gn_apply_t_kernel<<<dim3(64, 8, 8), 256, 0, stream>>>(x, gamma, beta, stats, xnt);
  // qk_t[b][l][o] = sum_c xn_t[b][l][c] * w_qkv[o][c] + b_qkv[o], o in [0,1024)
  gemm_tn<0><<<dim3(32, 8, 8), 256, 0, stream>>>(
      xnt, (long long)Ll * Cc, Cc, wqb, 0, Cc,
      qkt, (long long)Ll * 1024, 1024, b_qkv, nullptr, Cc);
  // v[b][c][l] = sum_cc w_qkv[1024+c][cc] * xn_t[b][l][cc] + b_qkv[1024+c]
  gemm_tn<1><<<dim3(4, 32, 8), 256, 0, stream>>>(
      wqb + (size_t)1024 * 512, 0, Cc, xnt, (long long)Ll * Cc, Cc,
      vbf, (long long)Cc * Ll, Ll, b_qkv + 1024, nullptr, Cc);
  flash_attn_kernel<<<256, 512, 0, stream>>>(qkt, vbf, ot);
  // out[b][o][l] = x + sum_c w_out[o][c] * o_t[b][l][c] + b_out[o]
  gemm_tn<2><<<dim3(4, 32, 8), 256, 0, stream>>>(
      wob, 0, Cc, ot, (long long)Ll * Cc, Cc,
      out, (long long)Cc * Ll, Ll, b_out, x, Cc);
}

// Round 11
// 642.304 us; speedup vs baseline: 1.7612x; 1.0403x over previous
//
#include <hip/hip_runtime.h>

typedef __attribute__((ext_vector_type(4))) float f32x4;
typedef __attribute__((ext_vector_type(8))) short short8;
typedef unsigned short u16;
typedef unsigned int u32;
typedef unsigned char u8;

// B=8, C=512, L=4096, GROUPS=8 (64 ch/group), EPS=1e-5
static constexpr int Bb = 8, Cc = 512, Ll = 4096;

__device__ __forceinline__ u16 f2bf(float f) {
  u32 u = __builtin_bit_cast(u32, f);
  u = (u + 0x7FFFu + ((u >> 16) & 1u)) >> 16;   // RTNE
  return (u16)u;
}

// saturating RTNE f32 -> OCP e4m3fn
__device__ __forceinline__ u8 f2e4m3(float f) {
  u32 u = __builtin_bit_cast(u32, f);
  u8 s = (u >> 24) & 0x80;
  float af = __builtin_fabsf(f);
  if (af >= 448.f) return s | 0x7E;          // saturate to max finite
  if (af < 0.015625f) {                      // subnormal: step 2^-9
    int n = (int)rintf(af * 512.f);
    return s | (u8)n;
  }
  u32 b = u & 0x7FFFFFFF;
  u32 r = b + 0x7FFFF + ((b >> 20) & 1);     // RTNE at mantissa bit 20
  int e = (int)(r >> 23) - 127;
  if (e > 8) return s | 0x7E;
  return s | (u8)(((e + 7) << 3) | ((r >> 20) & 7));
}

__device__ __forceinline__ void load_lds16(const void* g, void* l) {
  __builtin_amdgcn_global_load_lds((const __attribute__((address_space(1))) void*)g,
                                   (__attribute__((address_space(3))) void*)l,
                                   16, 0, 0);
}

// ---------------- weight fp32 -> bf16 ----------------
__global__ void cvt_bf16_kernel(const float* __restrict__ src, u16* __restrict__ dst, int n) {
  int stride = gridDim.x * blockDim.x;
  for (int i = blockIdx.x * blockDim.x + threadIdx.x; i < n; i += stride)
    dst[i] = f2bf(src[i]);
}

// ---------------- GroupNorm stats: one block per (b,g) ----------------
__global__ __launch_bounds__(256)
void gn_stats_kernel(const float* __restrict__ x, float* __restrict__ stats) {
  int bg = blockIdx.x;  // b*8+g ; group block is contiguous 64*4096 floats
  const f32x4* p = (const f32x4*)(x + (size_t)bg * (64 * Ll));
  float s = 0.f, ss = 0.f;
  for (int i = threadIdx.x; i < 64 * Ll / 4; i += 256) {
    f32x4 v = p[i];
    s  += v[0] + v[1] + v[2] + v[3];
    ss += v[0]*v[0] + v[1]*v[1] + v[2]*v[2] + v[3]*v[3];
  }
  __shared__ float rs[256], rq[256];
  rs[threadIdx.x] = s; rq[threadIdx.x] = ss;
  __syncthreads();
  for (int st = 128; st > 0; st >>= 1) {
    if (threadIdx.x < st) { rs[threadIdx.x] += rs[threadIdx.x + st]; rq[threadIdx.x] += rq[threadIdx.x + st]; }
    __syncthreads();
  }
  if (threadIdx.x == 0) {
    const float inv_n = 1.f / (64.f * 4096.f);
    float mean = rs[0] * inv_n;
    float var  = rq[0] * inv_n - mean * mean;
    stats[bg * 2]     = mean;
    stats[bg * 2 + 1] = rsqrtf(var + 1e-5f);
  }
}

// ------- GN apply + transpose: x[B,C,L] f32 -> xn_t[B,L,C] bf16 -------
__global__ __launch_bounds__(256)
void gn_apply_t_kernel(const float* __restrict__ x, const float* __restrict__ gamma,
                       const float* __restrict__ beta, const float* __restrict__ stats,
                       u16* __restrict__ xn_t) {
  int lt = blockIdx.x;   // l tile (64)
  int ct = blockIdx.y;   // c tile (64) == group index (64 ch/group)
  int b  = blockIdx.z;
  __shared__ float tile[64][65];
  int t = threadIdx.x;
  int lx = t & 63;       // lane within row
  int qd = t >> 6;       // quarter 0..3
  int c0 = ct * 64, l0 = lt * 64;
  float mean = stats[(b * 8 + ct) * 2];
  float rstd = stats[(b * 8 + ct) * 2 + 1];
  #pragma unroll
  for (int i = 0; i < 16; ++i) {
    int cl = qd + i * 4;
    int c = c0 + cl;
    float v = x[((size_t)b * Cc + c) * Ll + l0 + lx];
    tile[cl][lx] = (v - mean) * rstd * gamma[c] + beta[c];
  }
  __syncthreads();
  #pragma unroll
  for (int i = 0; i < 16; ++i) {
    int ll = qd + i * 4;
    xn_t[((size_t)b * Ll + l0 + ll) * Cc + c0 + lx] = f2bf(tile[lx][ll]);
  }
}

// ---------------- TN GEMM: D[m][n] = sum_k A[m][k]*Bm[n][k] ----------------
// A: [M][lda] bf16 (k contiguous), Bm: [N][ldb] bf16 (k contiguous).
// LDS layout granule-transposed for full-row b128 reads (R5-proven).
// MODE 0: bias[n], bf16 out. MODE 1: bias[m], bf16 out. MODE 2: bias[m]+resid, f32 out.
// MODE 3: bias[n], fp8 out split: n<512 -> Dv (q8), n>=512 -> resid-as-k8.
template <int MODE>
__global__ __launch_bounds__(256, 2)
void gemm_tn(const u16* __restrict__ A, long long aStride, int lda,
             const u16* __restrict__ Bm, long long bStride, int ldb,
             void* __restrict__ Dv, long long dStride, int ldd,
             const float* __restrict__ bias, const float* __restrict__ resid, int K) {
  int z = blockIdx.z;
  A  += (size_t)z * aStride;
  Bm += (size_t)z * bStride;
  int m0 = blockIdx.x * 128, n0 = blockIdx.y * 128;
  __shared__ uint4 sA[1024], sB[1024];
  int tid = threadIdx.x, lane = tid & 63;
  int wv = tid >> 6, wr = wv >> 1, wc = wv & 1;
  int l15 = lane & 15, l4 = lane >> 4;
  f32x4 acc[4][4] = {};
  for (int kt = 0; kt < K; kt += 64) {
    __syncthreads();
    #pragma unroll
    for (int p = 0; p < 4; ++p) {
      int s = p * 256 + tid;
      int r = ((s >> 7) << 4) | (((s >> 2) & 1) << 3) | ((s >> 3) & 7);
      int g = (((s >> 6) & 1) << 2) | (s & 3);
      load_lds16(A  + (size_t)(m0 + r) * lda + kt + g * 8, &sA[s]);
      load_lds16(Bm + (size_t)(n0 + r) * ldb + kt + g * 8, &sB[s]);
    }
    __syncthreads();
    #pragma unroll
    for (int ks = 0; ks < 2; ++ks) {
      short8 af[4], bfr[4];
      #pragma unroll
      for (int i = 0; i < 4; ++i) {
        int sa = (4 * wr + i) * 128 + ks * 64 + (l15 & 7) * 8 + (l15 >> 3) * 4 + l4;
        af[i]  = *(const short8*)&sA[sa];
        int sb = (4 * wc + i) * 128 + ks * 64 + (l15 & 7) * 8 + (l15 >> 3) * 4 + l4;
        bfr[i] = *(const short8*)&sB[sb];
      }
      #pragma unroll
      for (int i = 0; i < 4; ++i)
        #pragma unroll
        for (int j = 0; j < 4; ++j)
          acc[i][j] = __builtin_amdgcn_mfma_f32_16x16x32_bf16(af[i], bfr[j], acc[i][j], 0, 0, 0);
    }
  }
  #pragma unroll
  for (int i = 0; i < 4; ++i) {
    #pragma unroll
    for (int j = 0; j < 4; ++j) {
      #pragma unroll
      for (int r = 0; r < 4; ++r) {
        int m = m0 + 64 * wr + 16 * i + 4 * l4 + r;
        int n = n0 + 64 * wc + 16 * j + l15;
        float val = acc[i][j][r] + ((MODE == 0 || MODE == 3) ? bias[n] : bias[m]);
        if (MODE == 3) {
          u8* base = (n < 512) ? (u8*)Dv : (u8*)const_cast<float*>(resid);
          base[(size_t)z * dStride + (size_t)m * ldd + (n & 511)] = f2e4m3(val);
        } else {
          size_t idx = (size_t)z * dStride + (size_t)m * ldd + n;
          if (MODE == 2)      ((float*)Dv)[idx] = val + resid[idx];
          else                ((u16*)Dv)[idx]   = f2bf(val);
        }
      }
    }
  }
}

// ---------------- Flash attention (R10 structure, fp8 QK) ----------------
// q8/k8: [b][l][512] fp8 e4m3; v[b][c][l] bf16. Out: o_t[b][l][c] bf16.
// Grid: 256 blocks 1D; batch = bid & 7 (XCD-pinned). 48 KB/iter working set (L2 law ok).
__global__ __launch_bounds__(512, 2)
void flash_attn_kernel(const u8* __restrict__ q8, const u8* __restrict__ k8,
                       const u16* __restrict__ v, u16* __restrict__ o_t) {
  int bid = blockIdx.x;
  int b  = bid & 7;
  int q0 = (bid >> 3) * 128;
  int tid = threadIdx.x, lane = tid & 63, wv = tid >> 6;
  int l15 = lane & 15, l4 = lane >> 4;
  const u8* q8b = q8 + (size_t)b * Ll * 512;
  const u8* k8b = k8 + (size_t)b * Ll * 512;
  const u16* vb = v   + (size_t)b * Cc * Ll;
  u16* ob       = o_t + (size_t)b * Ll * Cc;

  __shared__ uint4 sK[2][1024];         // 2 x 16 KB fp8: [32 k-rows][32 granules], ^(r&15)
  __shared__ uint4 sV[2][512 * 4];      // 2 x 32 KB: [512 c-rows][4 granules], parity-XOR
  __shared__ __align__(16) char sP[128 * 80];  // P[128 q][32 k] bf16, row stride 80 B
  __shared__ __align__(16) float sAl[128];     // per-q rescale / final lrun

  int ow_q = wv >> 2, ow_c = wv & 3;    // PV-phase wave -> O tile [64 q][128 c]

  // Q fragments fp8 (B-operand of swapped QK): col=q=l15 of wave's 16-q block
  long aq[16];
  {
    const u8* qp = q8b + (size_t)(q0 + wv * 16 + l15) * 512 + 8 * l4;
    #pragma unroll
    for (int ks = 0; ks < 16; ++ks) aq[ks] = *(const long*)(qp + 32 * ks);
  }

  auto issueK = [&](int kt, int buf) {
    #pragma unroll
    for (int p = 0; p < 2; ++p) {
      int s = p * 512 + tid;             // 1024 granules of 16 B
      int r = s >> 5, g = s & 31;
      load_lds16(k8b + (size_t)(kt * 32 + r) * 512 + ((g ^ (r & 15)) << 4), &sK[buf][s]);
    }
  };
  auto issueV = [&](int kt, int buf) {
    #pragma unroll
    for (int p = 0; p < 4; ++p) {
      int s = p * 512 + tid;
      int r = s >> 2, g = s & 3, gw = g ^ ((r >> 1) & 3);
      load_lds16(vb + (size_t)r * Ll + kt * 32 + gw * 8, &sV[buf][s]);
    }
  };
  issueK(0, 0);
  issueV(0, 0);

  f32x4 accO[4][8];
  #pragma unroll
  for (int i = 0; i < 4; ++i)
    #pragma unroll
    for (int j = 0; j < 8; ++j) accO[i][j] = (f32x4){0.f, 0.f, 0.f, 0.f};
  float mrun = -1e30f, lrun = 0.f;      // lane owns q-row = l15 (of wave's 16-q block)
  const float scale = 0.044194173824159216f;  // 512^-0.5

  const int NT = Ll / 32;
  for (int kt = 0; kt < NT; ++kt) {
    int buf = kt & 1;
    __syncthreads();   // stage(kt) landed (issued a full iter ago); prev PV reads done
    if (kt + 1 < NT) { issueK(kt + 1, buf ^ 1); issueV(kt + 1, buf ^ 1); }

    // ---- QK^T swapped fp8: s2[t] = mfma(K_frag, Q) -> lane: S[k=16t+4*l4+r][q=l15] ----
    const u8* kb = (const u8*)&sK[buf][0];
    f32x4 s2[2];
    #pragma unroll
    for (int t = 0; t < 2; ++t) {
      s2[t] = (f32x4){0.f, 0.f, 0.f, 0.f};
      int row = 16 * t + l15;
      #pragma unroll
      for (int ks = 0; ks < 16; ++ks) {
        int gr = (2 * ks + (l4 >> 1)) ^ (row & 15);
        long ak = *(const long*)(kb + row * 512 + (gr << 4) + 8 * (l4 & 1));
        s2[t] = __builtin_amdgcn_mfma_f32_16x16x32_fp8_fp8(ak, aq[ks], s2[t], 0, 0, 0);
      }
    }

    // ---- online softmax over this 32k slice (q=l15 spread across l4 groups) ----
    #pragma unroll
    for (int t = 0; t < 2; ++t)
      #pragma unroll
      for (int r = 0; r < 4; ++r) s2[t][r] *= scale;
    float mx = fmaxf(fmaxf(s2[0][0], s2[0][1]), fmaxf(s2[0][2], s2[0][3]));
    mx = fmaxf(mx, fmaxf(fmaxf(s2[1][0], s2[1][1]), fmaxf(s2[1][2], s2[1][3])));
    mx = fmaxf(mx, __shfl_xor(mx, 16));
    mx = fmaxf(mx, __shfl_xor(mx, 32));
    float mnew = fmaxf(mrun, mx);
    float al = __expf(mrun - mnew);
    mrun = mnew;
    float ps = 0.f;
    #pragma unroll
    for (int t = 0; t < 2; ++t)
      #pragma unroll
      for (int r = 0; r < 4; ++r) { float pv = __expf(s2[t][r] - mnew); s2[t][r] = pv; ps += pv; }
    ps += __shfl_xor(ps, 16);
    ps += __shfl_xor(ps, 32);
    lrun = lrun * al + ps;

    // ---- P -> block-shared LDS (row stride 80 B, packed uint2) + al ----
    {
      char* pb = sP + (16 * wv + l15) * 80;
      #pragma unroll
      for (int t = 0; t < 2; ++t) {
        u32 lo = (u32)f2bf(s2[t][0]) | ((u32)f2bf(s2[t][1]) << 16);
        u32 hi = (u32)f2bf(s2[t][2]) | ((u32)f2bf(s2[t][3]) << 16);
        uint2 w = {lo, hi};
        *(uint2*)(pb + 32 * t + 8 * l4) = w;   // k = 16t+4*l4 .. +3 of row q
      }
      if (lane < 16) sAl[16 * wv + lane] = al;
    }

    // ---- publish P/al (lgkm only — staged prefetch stays in flight: T4) ----
    __builtin_amdgcn_sched_barrier(0);
    asm volatile("s_waitcnt lgkmcnt(0)" ::: "memory");
    __builtin_amdgcn_s_barrier();
    __builtin_amdgcn_sched_barrier(0);

    // ---- rescale accO rows by per-q factors ----
    #pragma unroll
    for (int i = 0; i < 4; ++i) {
      f32x4 av = *(const f32x4*)&sAl[64 * ow_q + 16 * i + 4 * l4];
      #pragma unroll
      for (int j = 0; j < 8; ++j) {
        #pragma unroll
        for (int r = 0; r < 4; ++r) accO[i][j][r] *= av[r];
      }
    }
    // ---- PV: O tile [64 q][128 c] per wave; A=P (shared), B=V; k-depth 32 = 1 MFMA ----
    short8 ap[4];
    #pragma unroll
    for (int i = 0; i < 4; ++i) {
      int ra = 64 * ow_q + 16 * i + l15;
      ap[i] = *(const short8*)(sP + ra * 80 + 16 * l4);
    }
    const uint4* vbuf = &sV[buf][0];
    #pragma unroll
    for (int j = 0; j < 8; ++j) {
      int crow = 128 * ow_c + 16 * j + l15;
      short8 bv = *(const short8*)&vbuf[crow * 4 + (l4 ^ ((crow >> 1) & 3))];
      #pragma unroll
      for (int i = 0; i < 4; ++i)
        accO[i][j] = __builtin_amdgcn_mfma_f32_16x16x32_bf16(ap[i], bv, accO[i][j], 0, 0, 0);
    }
  }

  // ---- relay lrun through sAl, normalize, write o_t[b][q][c] bf16 ----
  __syncthreads();
  if (lane < 16) sAl[16 * wv + lane] = lrun;
  __syncthreads();
  #pragma unroll
  for (int i = 0; i < 4; ++i) {
    f32x4 lv = *(const f32x4*)&sAl[64 * ow_q + 16 * i + 4 * l4];
    #pragma unroll
    for (int r = 0; r < 4; ++r) lv[r] = 1.f / lv[r];
    #pragma unroll
    for (int j = 0; j < 8; ++j) {
      #pragma unroll
      for (int r = 0; r < 4; ++r) {
        int q = q0 + 64 * ow_q + 16 * i + 4 * l4 + r;
        int c = 128 * ow_c + 16 * j + l15;
        ob[(size_t)q * Cc + c] = f2bf(accO[i][j][r] * lv[r]);
      }
    }
  }
}

extern "C" void kernel_launch(void* const* d_in, const int* in_sizes, int n_in,
                              void* d_out, int out_size, void* d_ws, size_t ws_size,
                              hipStream_t stream) {
  const float* x     = (const float*)d_in[0];
  const float* gamma = (const float*)d_in[1];
  const float* beta  = (const float*)d_in[2];
  const float* w_qkv = (const float*)d_in[3];
  const float* b_qkv = (const float*)d_in[4];
  const float* w_out = (const float*)d_in[5];
  const float* b_out = (const float*)d_in[6];
  float* out = (float*)d_out;

  char* ws = (char*)d_ws;
  size_t off = 0;
  auto alloc = [&](size_t bytes) -> char* {
    char* p = ws + off;
    off += (bytes + 1023) & ~(size_t)1023;
    return p;
  };
  float* stats = (float*)alloc(64 * 2 * sizeof(float));
  u16* wqb = (u16*)alloc((size_t)1536 * 512 * 2);
  u16* wob = (u16*)alloc((size_t)512 * 512 * 2);
  u16* xnt = (u16*)alloc((size_t)Bb * Ll * Cc * 2);   // [B][L][C]
  u8*  q8  = (u8*)alloc((size_t)Bb * Ll * 512);       // [B][L][512] fp8
  u8*  k8  = (u8*)alloc((size_t)Bb * Ll * 512);       // [B][L][512] fp8
  u16* vbf = (u16*)alloc((size_t)Bb * Cc * Ll * 2);   // [B][C][L]
  u16* ot  = xnt;  // reuse: xn_t dead after QKV GEMMs
  if (off > ws_size) return;  // workspace too small: fail loudly via validation

  cvt_bf16_kernel<<<256, 256, 0, stream>>>(w_qkv, wqb, 1536 * 512);
  cvt_bf16_kernel<<<256, 256, 0, stream>>>(w_out, wob, 512 * 512);
  gn_stats_kernel<<<64, 256, 0, stream>>>(x, stats);
  gn_apply_t_kernel<<<dim3(64, 8, 8), 256, 0, stream>>>(x, gamma, beta, stats, xnt);
  // q8/k8[b][l][c] = fp8(sum_cc xn_t[b][l][cc]*w_qkv[o][cc] + b_qkv[o]), o in [0,1024)
  gemm_tn<3><<<dim3(32, 8, 8), 256, 0, stream>>>(
      xnt, (long long)Ll * Cc, Cc, wqb, 0, Cc,
      q8, (long long)Ll * 512, 512, b_qkv, (const float*)k8, Cc);
  // v[b][c][l] = sum_cc w_qkv[1024+c][cc] * xn_t[b][l][cc] + b_qkv[1024+c]
  gemm_tn<1><<<dim3(4, 32, 8), 256, 0, stream>>>(
      wqb + (size_t)1024 * 512, 0, Cc, xnt, (long long)Ll * Cc, Cc,
      vbf, (long long)Cc * Ll, Ll, b_qkv + 1024, nullptr, Cc);
  flash_attn_kernel<<<256, 512, 0, stream>>>(q8, k8, vbf, ot);
  // out[b][o][l] = x + sum_c w_out[o][c] * o_t[b][l][c] + b_out[o]
  gemm_tn<2><<<dim3(4, 32, 8), 256, 0, stream>>>(
      wob, 0, Cc, ot, (long long)Ll * Cc, Cc,
      out, (long long)Cc * Ll, Ll, b_out, x, Cc);
}